// Round 1
// baseline (1231.495 us; speedup 1.0000x reference)
//
#include <hip/hip_runtime.h>
#include <cstdint>
#include <cstddef>

#define DIM 384
#define HEADS 8
#define NBATCH 8
#define NPIX 16384   // 128*128
#define CPH 48       // channels per head

typedef unsigned short h16_t;   // fp16 bits
typedef __attribute__((ext_vector_type(8))) _Float16 half8;
typedef __attribute__((ext_vector_type(4))) float floatx4;

__device__ __forceinline__ h16_t f2h(float f) {
  _Float16 h = (_Float16)f;          // v_cvt_f16_f32, RNE
  return __builtin_bit_cast(h16_t, h);
}
__device__ __forceinline__ float h2f(h16_t u) {
  return (float)__builtin_bit_cast(_Float16, u);
}

__device__ __forceinline__ void gload_lds16(const void* g, void* l) {
  __builtin_amdgcn_global_load_lds(
      (const __attribute__((address_space(1))) unsigned int*)g,
      (__attribute__((address_space(3))) unsigned int*)l, 16, 0, 0);
}

// ---------------------------------------------------------------------------
// fp32 -> fp16 elementwise convert (weights)
// ---------------------------------------------------------------------------
__global__ void convert_h16_kernel(const float* __restrict__ in, h16_t* __restrict__ out, int n) {
  int i = blockIdx.x * blockDim.x + threadIdx.x;
  if (i < n) out[i] = f2h(in[i]);
}

// ---------------------------------------------------------------------------
// fp16 MFMA GEMM with in-LDS B transpose (gemm_tn):
//   C[b][m][n] = sum_k A[m][k] * B[b][k][n]
// A: [384][384] fp16 K-contiguous (ABATCH -> per-batch stride 384*384)
// B: [b][384][16384], K-major (native conv layout). BT = float or h16.
//    B tile [64 k][128 n] is transposed into LDS [128 n][64 k] during staging
//    (reg-staged, fp16-converted), rows padded to 144 B (9x16B) so both the
//    ds_write_b128 (bank-quad (n+koct)&7, 8 lanes each) and the fragment
//    ds_read_b128 ((n+chunk)&7 over 16 rows) are conflict-free without XOR.
// A keeps the proven global_load_lds + XOR-swizzle path.
// grid: (16384/128, 384/128, 8), block 256 (4 waves, 2x2, each 64x64)
// ---------------------------------------------------------------------------
template <bool F32OUT, bool ABATCH, typename BT>
__global__ __launch_bounds__(256) void gemm_tn_kernel(
    const h16_t* __restrict__ Aall, const BT* __restrict__ Ball, void* __restrict__ Cout) {
  __shared__ __align__(16) h16_t lA[128 * 64];   // [128 m][64 k], 128 B rows, XOR chunks
  __shared__ __align__(16) h16_t lB[128 * 72];   // [128 n][72], 144 B rows (64 k + 8 pad)
  int b = blockIdx.z, mb = blockIdx.y, nb = blockIdx.x;
  const h16_t* A = Aall + (ABATCH ? (size_t)b * DIM * DIM : (size_t)0) + (size_t)mb * 128 * DIM;
  const BT* B = Ball + (size_t)b * DIM * NPIX + (size_t)nb * 128;
  int tid = threadIdx.x;
  int wid = tid >> 6, lane = tid & 63;
  int wi = wid >> 1, wj = wid & 1;
  int quad = lane >> 4, l15 = lane & 15;
  int srow = lane >> 3;                  // 0..7
  int schunk = (lane & 7) ^ srow;        // A XOR swizzle: logical 16B chunk fetched
  int koct = tid & 7;                    // B staging: channel octet (8 k each)
  int n4 = tid >> 3;                     // B staging: pixel quad (0..31)

  float4 f[8];
  ushort4 u[8];
  auto loadB = [&](int ktL) {
    const BT* bp = B + (size_t)(ktL * 64 + koct * 8) * NPIX + (size_t)n4 * 4;
#pragma unroll
    for (int i = 0; i < 8; ++i) {
      if constexpr (sizeof(BT) == 4)
        f[i] = *(const float4*)(bp + (size_t)i * NPIX);
      else
        u[i] = *(const ushort4*)(bp + (size_t)i * NPIX);
    }
  };

  floatx4 acc[4][4];
#pragma unroll
  for (int i = 0; i < 4; ++i)
#pragma unroll
    for (int j = 0; j < 4; ++j) acc[i][j] = (floatx4)0.0f;

  loadB(0);
  for (int kt = 0; kt < 6; ++kt) {  // K = 384 = 6 * 64
    __syncthreads();                 // previous tile's compute done, LDS free
    // convert + transpose-write B tile (regs from previous iteration's loads)
    half8 w0, w1, w2, w3;            // w_j[i] = half(ch koct*8+i, pixel n4*4+j)
#pragma unroll
    for (int i = 0; i < 8; ++i) {
      if constexpr (sizeof(BT) == 4) {
        w0[i] = (_Float16)f[i].x; w1[i] = (_Float16)f[i].y;
        w2[i] = (_Float16)f[i].z; w3[i] = (_Float16)f[i].w;
      } else {
        w0[i] = __builtin_bit_cast(_Float16, u[i].x);
        w1[i] = __builtin_bit_cast(_Float16, u[i].y);
        w2[i] = __builtin_bit_cast(_Float16, u[i].z);
        w3[i] = __builtin_bit_cast(_Float16, u[i].w);
      }
    }
    {
      char* bb = (char*)lB + n4 * (4 * 144) + koct * 16;
      *(half8*)(bb + 0)   = w0;
      *(half8*)(bb + 144) = w1;
      *(half8*)(bb + 288) = w2;
      *(half8*)(bb + 432) = w3;
    }
    // stage A via global_load_lds (linear dest, pre-swizzled source)
#pragma unroll
    for (int t = 0; t < 4; ++t) {
      int r = (wid * 4 + t) * 8 + srow;  // tile row 0..127
      gload_lds16(A + (size_t)r * DIM + kt * 64 + schunk * 8,
                  (char*)lA + (wid * 4 + t) * 1024 + lane * 16);
    }
    __syncthreads();                 // tile kt ready (drains vm+lgkm)
    if (kt < 5) loadB(kt + 1);       // next tile's B flies under the MFMAs
#pragma unroll
    for (int ks = 0; ks < 2; ++ks) {
      half8 af[4], bfr[4];
      int ph = (((ks << 2) | quad) ^ (l15 & 7)) << 4;  // A: XOR-swizzled chunk
      int pb = (((ks << 2) | quad)) << 4;              // B: linear chunk, padded rows
#pragma unroll
      for (int i = 0; i < 4; ++i)
        af[i] = *(const half8*)((const char*)lA + (wi * 64 + i * 16 + l15) * 128 + ph);
#pragma unroll
      for (int j = 0; j < 4; ++j)
        bfr[j] = *(const half8*)((const char*)lB + (wj * 64 + j * 16 + l15) * 144 + pb);
#pragma unroll
      for (int i = 0; i < 4; ++i)
#pragma unroll
        for (int j = 0; j < 4; ++j)
          acc[i][j] = __builtin_amdgcn_mfma_f32_16x16x32_f16(af[i], bfr[j], acc[i][j], 0, 0, 0);
    }
  }
  // epilogue: D row = A-row (m, o-dim), col = B-col (n-dim)
  int orow0 = mb * 128 + wi * 64 + quad * 4;
  int ncol0 = nb * 128 + wj * 64 + l15;
#pragma unroll
  for (int i = 0; i < 4; ++i) {
#pragma unroll
    for (int j = 0; j < 4; ++j) {
#pragma unroll
      for (int r = 0; r < 4; ++r) {
        size_t idx = ((size_t)b * DIM + (orow0 + i * 16 + r)) * NPIX + (ncol0 + j * 16);
        if (F32OUT)
          ((float*)Cout)[idx] = acc[i][j][r];
        else
          ((h16_t*)Cout)[idx] = f2h(acc[i][j][r]);
      }
    }
  }
}

// ---------------------------------------------------------------------------
// Depthwise 3x3, SAME padding, fp16 in/out, fp32 weights & arithmetic.
// Optionally accumulates sum of squares (of the fp16-rounded outputs) per plane.
// grid: (C=384, b=8), block 256. Each block = one (b,c) 128x128 plane.
// ---------------------------------------------------------------------------
__device__ __forceinline__ void load_row6(const h16_t* ip, int yy, int x0, float* r) {
  if ((unsigned)yy > 127u) {
    r[0] = r[1] = r[2] = r[3] = r[4] = r[5] = 0.f;
    return;
  }
  const h16_t* row = ip + (yy << 7) + x0;
  ushort4 m = *(const ushort4*)row;
  r[0] = (x0 > 0) ? h2f(row[-1]) : 0.f;
  r[1] = h2f(m.x); r[2] = h2f(m.y); r[3] = h2f(m.z); r[4] = h2f(m.w);
  r[5] = (x0 < 124) ? h2f(row[4]) : 0.f;
}

__global__ __launch_bounds__(256) void dwconv_kernel(
    const h16_t* __restrict__ in, const float* __restrict__ wbase,
    h16_t* __restrict__ out, float* __restrict__ norm2) {
  int c = blockIdx.x, b = blockIdx.y;
  const h16_t* ip = in + ((size_t)(b * DIM + c) << 14);
  h16_t* op = out + ((size_t)(b * DIM + c) << 14);
  const float* wp = wbase + c * 9;
  float w0 = wp[0], w1 = wp[1], w2 = wp[2], w3 = wp[3], w4 = wp[4];
  float w5 = wp[5], w6 = wp[6], w7 = wp[7], w8 = wp[8];
  float ssum = 0.f;
  for (int t = threadIdx.x; t < 4096; t += 256) {
    int y = t >> 5;
    int x0 = (t & 31) << 2;
    float r0[6], r1[6], r2[6];
    load_row6(ip, y - 1, x0, r0);
    load_row6(ip, y,     x0, r1);
    load_row6(ip, y + 1, x0, r2);
    ushort4 st;
#pragma unroll
    for (int i = 0; i < 4; ++i) {
      float o = w0 * r0[i] + w1 * r0[i + 1] + w2 * r0[i + 2]
              + w3 * r1[i] + w4 * r1[i + 1] + w5 * r1[i + 2]
              + w6 * r2[i] + w7 * r2[i + 1] + w8 * r2[i + 2];
      h16_t ob = f2h(o);
      float of = h2f(ob);
      ssum += of * of;
      if (i == 0) st.x = ob; else if (i == 1) st.y = ob; else if (i == 2) st.z = ob; else st.w = ob;
    }
    *(ushort4*)(op + (y << 7) + x0) = st;
  }
  if (norm2 != nullptr) {
    __shared__ float red[256];
    int tid = threadIdx.x;
    red[tid] = ssum;
    __syncthreads();
    for (int s = 128; s > 0; s >>= 1) {
      if (tid < s) red[tid] += red[tid + s];
      __syncthreads();
    }
    if (tid == 0) norm2[b * DIM + c] = red[0];
  }
}

// ---------------------------------------------------------------------------
// attn Gram: attn[bh][c][d] += sum_n q[b][h*48+c][n] * k[b][h*48+d][n]
// q,k fp16 [b][384][16384] (n-contiguous = K-contiguous: register-direct MFMA)
// grid: (16 K-chunks, 64 bh), block 64 (1 wave, 3x3 16-tiles). fp32 atomics.
// 16 chunks -> 1024 waves = 4 waves/CU for latency hiding.
// ---------------------------------------------------------------------------
__global__ __launch_bounds__(64) void attn_gemm_kernel(
    const h16_t* __restrict__ q, const h16_t* __restrict__ k, float* __restrict__ attn) {
  int chunk = blockIdx.x, bh = blockIdx.y;
  int b = bh >> 3, h = bh & 7;
  const h16_t* qb = q + ((size_t)(b * DIM + h * CPH) << 14);
  const h16_t* kb = k + ((size_t)(b * DIM + h * CPH) << 14);
  int lane = threadIdx.x;
  int quad = lane >> 4, l15 = lane & 15;
  int off0 = chunk * 1024 + quad * 8;
  floatx4 acc[3][3];
#pragma unroll
  for (int i = 0; i < 3; ++i)
#pragma unroll
    for (int j = 0; j < 3; ++j) acc[i][j] = (floatx4)0.0f;
  for (int s = 0; s < 32; ++s) {
    int off = off0 + s * 32;
    half8 af[3], bfr[3];
#pragma unroll
    for (int i = 0; i < 3; ++i) {
      af[i]  = *(const half8*)(qb + ((size_t)(i * 16 + l15) << 14) + off);
      bfr[i] = *(const half8*)(kb + ((size_t)(i * 16 + l15) << 14) + off);
    }
#pragma unroll
    for (int i = 0; i < 3; ++i)
#pragma unroll
      for (int j = 0; j < 3; ++j)
        acc[i][j] = __builtin_amdgcn_mfma_f32_16x16x32_f16(af[i], bfr[j], acc[i][j], 0, 0, 0);
  }
  float* ap = attn + (size_t)bh * CPH * CPH;
#pragma unroll
  for (int i = 0; i < 3; ++i)
#pragma unroll
    for (int j = 0; j < 3; ++j)
#pragma unroll
      for (int r = 0; r < 4; ++r)
        atomicAdd(&ap[(i * 16 + quad * 4 + r) * CPH + j * 16 + l15], acc[i][j][r]);
}

// ---------------------------------------------------------------------------
// Per-(b,h): scale attn by 1/(|q||k|)*temp, 4x top-m softmax combined with a_mix,
// then fold with proj_w: Bmat[b][o][h*48+d] = sum_c proj_w[o][h*48+c]*Acomb[c][d]
// grid: 64 blocks, 256 threads
// ---------------------------------------------------------------------------
__global__ __launch_bounds__(256) void combine_kernel(
    const float* __restrict__ attn, const float* __restrict__ n2q, const float* __restrict__ n2k,
    const float* __restrict__ temp, const float* __restrict__ amix,
    const float* __restrict__ projw, h16_t* __restrict__ Bmat) {
  int bh = blockIdx.x;
  int b = bh >> 3, h = bh & 7;
  __shared__ float Asc[CPH][CPH];
  __shared__ float Ex[CPH][CPH];
  __shared__ float thr[CPH][4];
  __shared__ float rmax[CPH];
  __shared__ float den[CPH][4];
  __shared__ float rsq[CPH], rsk[CPH];
  int tid = threadIdx.x;
  if (tid < CPH) {
    float nq = sqrtf(n2q[b * DIM + h * CPH + tid]);
    rsq[tid] = 1.f / fmaxf(nq, 1e-12f);
    float nk = sqrtf(n2k[b * DIM + h * CPH + tid]);
    rsk[tid] = 1.f / fmaxf(nk, 1e-12f);
  }
  __syncthreads();
  float tscale = temp[h];
  const float* ap = attn + (size_t)bh * CPH * CPH;
  for (int idx = tid; idx < CPH * CPH; idx += 256) {
    int c = idx / CPH, d = idx - c * CPH;
    Asc[c][d] = ap[idx] * rsq[c] * rsk[d] * tscale;
  }
  __syncthreads();
  const int M0 = 24, M1 = 32, M2 = 36, M3 = 38;  // C//2, 2C//3, 3C//4, 4C//5
  for (int idx = tid; idx < CPH * CPH; idx += 256) {
    int c = idx / CPH, d = idx - c * CPH;
    float a = Asc[c][d];
    int gt = 0, ge = 0;
    float mx = -1e30f;
    for (int e = 0; e < CPH; ++e) {
      float v = Asc[c][e];
      gt += (v > a);
      ge += (v >= a);
      mx = fmaxf(mx, v);
    }
    if (d == 0) rmax[c] = mx;
    // a is the m-th largest iff (#>a) < m <= (#>=a); ties write identical bits
    if (gt < M0 && ge >= M0) thr[c][0] = a;
    if (gt < M1 && ge >= M1) thr[c][1] = a;
    if (gt < M2 && ge >= M2) thr[c][2] = a;
    if (gt < M3 && ge >= M3) thr[c][3] = a;
  }
  __syncthreads();
  for (int idx = tid; idx < CPH * CPH; idx += 256) {
    int c = idx / CPH, d = idx - c * CPH;
    Ex[c][d] = expf(Asc[c][d] - rmax[c]);
  }
  __syncthreads();
  if (tid < CPH * 4) {
    int c = tid >> 2, mi = tid & 3;
    float t_ = thr[c][mi];
    float s = 0.f;
    for (int e = 0; e < CPH; ++e)
      if (Asc[c][e] >= t_) s += Ex[c][e];
    den[c][mi] = s;
  }
  __syncthreads();
  float a0 = amix[0], a1 = amix[1], a2 = amix[2], a3 = amix[3];
  for (int idx = tid; idx < CPH * CPH; idx += 256) {
    int c = idx / CPH, d = idx - c * CPH;
    float a = Asc[c][d];
    float s = 0.f;
    if (a >= thr[c][0]) s += a0 / den[c][0];
    if (a >= thr[c][1]) s += a1 / den[c][1];
    if (a >= thr[c][2]) s += a2 / den[c][2];
    if (a >= thr[c][3]) s += a3 / den[c][3];
    Ex[c][d] = Ex[c][d] * s;  // Acomb
  }
  __syncthreads();
  for (int idx = tid; idx < DIM * CPH; idx += 256) {
    int o = idx / CPH, d = idx - (idx / CPH) * CPH;
    const float* pw = projw + (size_t)o * DIM + h * CPH;
    float s = 0.f;
    for (int c2 = 0; c2 < CPH; ++c2) s += pw[c2] * Ex[c2][d];
    Bmat[((size_t)b * DIM + o) * DIM + h * CPH + d] = f2h(s);
  }
}

// ---------------------------------------------------------------------------
extern "C" void kernel_launch(void* const* d_in, const int* in_sizes, int n_in,
                              void* d_out, int out_size, void* d_ws, size_t ws_size,
                              hipStream_t stream) {
  const float* x_q    = (const float*)d_in[0];
  const float* x_kv   = (const float*)d_in[1];
  const float* q_w    = (const float*)d_in[2];
  const float* q_dw   = (const float*)d_in[3];
  const float* kv_w   = (const float*)d_in[4];
  const float* kv_dw  = (const float*)d_in[5];
  const float* proj_w = (const float*)d_in[6];
  const float* temp   = (const float*)d_in[7];
  const float* amix   = (const float*)d_in[8];

  char* ws = (char*)d_ws;
  const size_t SLOT = (size_t)NBATCH * NPIX * DIM * 2;  // 100,663,296 B
  h16_t* S0 = (h16_t*)(ws);             // Yq -> Yk
  h16_t* S1 = (h16_t*)(ws + SLOT);      // Yv
  h16_t* S2 = (h16_t*)(ws + 2 * SLOT);  // q -> v
  h16_t* S3 = (h16_t*)(ws + 3 * SLOT);  // k
  char* p = ws + 4 * SLOT;
  h16_t* WqB  = (h16_t*)p; p += (size_t)DIM * DIM * 2;
  h16_t* WkvB = (h16_t*)p; p += (size_t)2 * DIM * DIM * 2;
  float* n2q  = (float*)p;  p += (size_t)NBATCH * DIM * 4;
  float* n2k  = (float*)p;  p += (size_t)NBATCH * DIM * 4;
  float* attn = (float*)p;  p += (size_t)64 * CPH * CPH * 4;
  h16_t* Bmat = (h16_t*)p; p += (size_t)NBATCH * DIM * DIM * 2;

  hipMemsetAsync(attn, 0, (size_t)64 * CPH * CPH * 4, stream);

  convert_h16_kernel<<<dim3((DIM * DIM + 255) / 256), 256, 0, stream>>>(q_w, WqB, DIM * DIM);
  convert_h16_kernel<<<dim3((2 * DIM * DIM + 255) / 256), 256, 0, stream>>>(kv_w, WkvB, 2 * DIM * DIM);

  dim3 ggrid(NPIX / 128, DIM / 128, NBATCH);

  // q path (GEMM reads fp32 x_q directly, transposes in LDS)
  gemm_tn_kernel<false, false, float><<<ggrid, 256, 0, stream>>>(WqB, x_q, S0);
  dwconv_kernel<<<dim3(DIM, NBATCH), 256, 0, stream>>>(S0, q_dw, S2, n2q);

  // k and v GEMMs back-to-back: second x_kv read (201 MB < 256 MB L3) hits L3
  gemm_tn_kernel<false, false, float><<<ggrid, 256, 0, stream>>>(WkvB, x_kv, S0);
  gemm_tn_kernel<false, false, float><<<ggrid, 256, 0, stream>>>(WkvB + (size_t)DIM * DIM, x_kv, S1);
  dwconv_kernel<<<dim3(DIM, NBATCH), 256, 0, stream>>>(S0, kv_dw, S3, n2k);

  // attention (48x48 per b,h) + top-m combine + proj fold
  attn_gemm_kernel<<<dim3(16, 64), 64, 0, stream>>>(S2, S3, attn);
  combine_kernel<<<dim3(64), 256, 0, stream>>>(attn, n2q, n2k, temp, amix, proj_w, Bmat);

  // v path (q in S2 is dead after attn)
  dwconv_kernel<<<dim3(DIM, NBATCH), 256, 0, stream>>>(S1, kv_dw + (size_t)DIM * 9, S2, nullptr);

  // fused (proj ∘ attn-mix) @ v -> d_out fp32; B = v fp16 [b][c][n], LDS-transposed
  gemm_tn_kernel<true, true, h16_t><<<ggrid, 256, 0, stream>>>(Bmat, S2, d_out);
}

// Round 2
// 1207.704 us; speedup vs baseline: 1.0197x; 1.0197x over previous
//
#include <hip/hip_runtime.h>
#include <cstdint>
#include <cstddef>

#define DIM 384
#define HEADS 8
#define NBATCH 8
#define NPIX 16384   // 128*128
#define CPH 48       // channels per head

typedef unsigned short h16_t;   // fp16 bits
typedef __attribute__((ext_vector_type(8))) _Float16 half8;
typedef __attribute__((ext_vector_type(4))) float floatx4;

#define VM_WAIT(n) asm volatile("s_waitcnt vmcnt(" #n ")" ::: "memory")
#define LGKM_WAIT0 asm volatile("s_waitcnt lgkmcnt(0)" ::: "memory")

__device__ __forceinline__ h16_t f2h(float f) {
  _Float16 h = (_Float16)f;          // v_cvt_f16_f32, RNE
  return __builtin_bit_cast(h16_t, h);
}
__device__ __forceinline__ float h2f(h16_t u) {
  return (float)__builtin_bit_cast(_Float16, u);
}

__device__ __forceinline__ void gload_lds16(const void* g, void* l) {
  __builtin_amdgcn_global_load_lds(
      (const __attribute__((address_space(1))) unsigned int*)g,
      (__attribute__((address_space(3))) unsigned int*)l, 16, 0, 0);
}

// ---------------------------------------------------------------------------
// fp32 -> fp16 elementwise convert (weights)
// ---------------------------------------------------------------------------
__global__ void convert_h16_kernel(const float* __restrict__ in, h16_t* __restrict__ out, int n) {
  int i = blockIdx.x * blockDim.x + threadIdx.x;
  if (i < n) out[i] = f2h(in[i]);
}

// ---------------------------------------------------------------------------
// fp16 MFMA GEMM with in-LDS B transpose (gemm_tn):
//   C[b][m][n] = sum_k A[m][k] * B[b][k][n]
// A: [384][384] fp16 K-contiguous (ABATCH -> per-batch stride 384*384)
// B: [b][384][16384], K-major (native conv layout). BT = float or h16.
//
// Round-1 post-mortem: __syncthreads() drains vmcnt(0) every K-tile, exposing
// the A-staging latency + leaving only the MFMA window for B's HBM latency
// (MfmaUtil 12%, VALUBusy 19%, hbm 22% -> latency-bound). This version uses
// the counted-vmcnt 2-phase schedule (T3/T4 minimum):
//   - lA double-buffered; A[kt+1] global_load_lds issued at top of iter kt,
//     in flight for a full iteration; steady-state wait is vmcnt(4), never 0.
//   - lB single-buffered (write->lgkmcnt(0)->barrier->read; end barrier
//     separates read from next write).
//   - B[kt+1] global loads reissued into the same reg set right after cvt
//     consumes it; they fly under the MFMA cluster and the next barrier.
// Math order identical to round 1 -> bit-identical output expected.
// grid: (16384/128, 384/128, 8), block 256 (4 waves, 2x2, each 64x64)
// ---------------------------------------------------------------------------
template <bool F32OUT, bool ABATCH, typename BT>
__global__ __launch_bounds__(256, 3) void gemm_tn_kernel(
    const h16_t* __restrict__ Aall, const BT* __restrict__ Ball, void* __restrict__ Cout) {
  __shared__ __align__(16) h16_t lA[2][128 * 64];  // 2 x 16 KB, XOR-chunk layout
  __shared__ __align__(16) h16_t lB[128 * 72];     // 18 KB, 144 B rows (64 k + pad)
  int b = blockIdx.z, mb = blockIdx.y, nb = blockIdx.x;
  const h16_t* A = Aall + (ABATCH ? (size_t)b * DIM * DIM : (size_t)0) + (size_t)mb * 128 * DIM;
  const BT* B = Ball + (size_t)b * DIM * NPIX + (size_t)nb * 128;
  int tid = threadIdx.x;
  int wid = tid >> 6, lane = tid & 63;
  int wi = wid >> 1, wj = wid & 1;
  int quad = lane >> 4, l15 = lane & 15;
  int srow = lane >> 3;                  // 0..7
  int schunk = (lane & 7) ^ srow;        // A XOR swizzle: logical 16B chunk fetched
  int koct = tid & 7;                    // B staging: channel octet (8 k each)
  int n4 = tid >> 3;                     // B staging: pixel quad (0..31)

  float4 f[8];
  ushort4 u[8];
  auto loadB = [&](int ktL) {
    const BT* bp = B + (size_t)(ktL * 64 + koct * 8) * NPIX + (size_t)n4 * 4;
#pragma unroll
    for (int i = 0; i < 8; ++i) {
      if constexpr (sizeof(BT) == 4)
        f[i] = *(const float4*)(bp + (size_t)i * NPIX);
      else
        u[i] = *(const ushort4*)(bp + (size_t)i * NPIX);
    }
  };
  auto stageA = [&](int ktL, int buf) {
#pragma unroll
    for (int t = 0; t < 4; ++t) {
      int r = (wid * 4 + t) * 8 + srow;  // tile row 0..127
      gload_lds16(A + (size_t)r * DIM + ktL * 64 + schunk * 8,
                  (char*)&lA[buf][0] + (wid * 4 + t) * 1024 + lane * 16);
    }
  };

  floatx4 acc[4][4];
#pragma unroll
  for (int i = 0; i < 4; ++i)
#pragma unroll
    for (int j = 0; j < 4; ++j) acc[i][j] = (floatx4)0.0f;

  // prologue: outstanding vm queue = [A0(4), B0(8)]
  stageA(0, 0);
  loadB(0);

#pragma unroll
  for (int kt = 0; kt < 6; ++kt) {  // K = 384 = 6 * 64
    const int c = kt & 1;
    // 1. next A tile into the other buffer (queue: A_kt, B_kt, A_kt+1)
    if (kt < 5) stageA(kt + 1, 1 - c);
    // 2. wait for A_kt (into lA[c]) + B_kt (regs); leave A_kt+1 in flight
    if (kt < 5) { VM_WAIT(4); } else { VM_WAIT(0); }
    __builtin_amdgcn_sched_barrier(0);
    // 3. convert + transpose-write B tile
    half8 w0, w1, w2, w3;            // w_j[i] = half(ch koct*8+i, pixel n4*4+j)
#pragma unroll
    for (int i = 0; i < 8; ++i) {
      if constexpr (sizeof(BT) == 4) {
        w0[i] = (_Float16)f[i].x; w1[i] = (_Float16)f[i].y;
        w2[i] = (_Float16)f[i].z; w3[i] = (_Float16)f[i].w;
      } else {
        w0[i] = __builtin_bit_cast(_Float16, u[i].x);
        w1[i] = __builtin_bit_cast(_Float16, u[i].y);
        w2[i] = __builtin_bit_cast(_Float16, u[i].z);
        w3[i] = __builtin_bit_cast(_Float16, u[i].w);
      }
    }
    {
      char* bb = (char*)lB + n4 * (4 * 144) + koct * 16;
      *(half8*)(bb + 0)   = w0;
      *(half8*)(bb + 144) = w1;
      *(half8*)(bb + 288) = w2;
      *(half8*)(bb + 432) = w3;
    }
    // 4. reissue B regs for next tile (flies under MFMAs; queue: A_kt+1, B_kt+1)
    if (kt < 5) loadB(kt + 1);
    // 5. my ds_writes visible, then rendezvous (no vm drain!)
    LGKM_WAIT0;
    __builtin_amdgcn_sched_barrier(0);
    __builtin_amdgcn_s_barrier();
    // 6. compute tile kt
#pragma unroll
    for (int ks = 0; ks < 2; ++ks) {
      half8 af[4], bfr[4];
      int ph = (((ks << 2) | quad) ^ (l15 & 7)) << 4;  // A: XOR-swizzled chunk
      int pb = (((ks << 2) | quad)) << 4;              // B: linear chunk, padded rows
#pragma unroll
      for (int i = 0; i < 4; ++i)
        af[i] = *(const half8*)((const char*)&lA[c][0] + (wi * 64 + i * 16 + l15) * 128 + ph);
#pragma unroll
      for (int j = 0; j < 4; ++j)
        bfr[j] = *(const half8*)((const char*)lB + (wj * 64 + j * 16 + l15) * 144 + pb);
#pragma unroll
      for (int i = 0; i < 4; ++i)
#pragma unroll
        for (int j = 0; j < 4; ++j)
          acc[i][j] = __builtin_amdgcn_mfma_f32_16x16x32_f16(af[i], bfr[j], acc[i][j], 0, 0, 0);
    }
    // 7. all lds reads done before next iter overwrites lB / stages lA[1-c]
    LGKM_WAIT0;
    __builtin_amdgcn_sched_barrier(0);
    __builtin_amdgcn_s_barrier();
  }
  // epilogue: D row = A-row (m, o-dim), col = B-col (n-dim)
  int orow0 = mb * 128 + wi * 64 + quad * 4;
  int ncol0 = nb * 128 + wj * 64 + l15;
#pragma unroll
  for (int i = 0; i < 4; ++i) {
#pragma unroll
    for (int j = 0; j < 4; ++j) {
#pragma unroll
      for (int r = 0; r < 4; ++r) {
        size_t idx = ((size_t)b * DIM + (orow0 + i * 16 + r)) * NPIX + (ncol0 + j * 16);
        if (F32OUT)
          ((float*)Cout)[idx] = acc[i][j][r];
        else
          ((h16_t*)Cout)[idx] = f2h(acc[i][j][r]);
      }
    }
  }
}

// ---------------------------------------------------------------------------
// Depthwise 3x3, SAME padding, fp16 in/out, fp32 weights & arithmetic.
// Optionally accumulates sum of squares (of the fp16-rounded outputs) per plane.
// grid: (C=384, b=8), block 256. Each block = one (b,c) 128x128 plane.
// ---------------------------------------------------------------------------
__device__ __forceinline__ void load_row6(const h16_t* ip, int yy, int x0, float* r) {
  if ((unsigned)yy > 127u) {
    r[0] = r[1] = r[2] = r[3] = r[4] = r[5] = 0.f;
    return;
  }
  const h16_t* row = ip + (yy << 7) + x0;
  ushort4 m = *(const ushort4*)row;
  r[0] = (x0 > 0) ? h2f(row[-1]) : 0.f;
  r[1] = h2f(m.x); r[2] = h2f(m.y); r[3] = h2f(m.z); r[4] = h2f(m.w);
  r[5] = (x0 < 124) ? h2f(row[4]) : 0.f;
}

__global__ __launch_bounds__(256) void dwconv_kernel(
    const h16_t* __restrict__ in, const float* __restrict__ wbase,
    h16_t* __restrict__ out, float* __restrict__ norm2) {
  int c = blockIdx.x, b = blockIdx.y;
  const h16_t* ip = in + ((size_t)(b * DIM + c) << 14);
  h16_t* op = out + ((size_t)(b * DIM + c) << 14);
  const float* wp = wbase + c * 9;
  float w0 = wp[0], w1 = wp[1], w2 = wp[2], w3 = wp[3], w4 = wp[4];
  float w5 = wp[5], w6 = wp[6], w7 = wp[7], w8 = wp[8];
  float ssum = 0.f;
  for (int t = threadIdx.x; t < 4096; t += 256) {
    int y = t >> 5;
    int x0 = (t & 31) << 2;
    float r0[6], r1[6], r2[6];
    load_row6(ip, y - 1, x0, r0);
    load_row6(ip, y,     x0, r1);
    load_row6(ip, y + 1, x0, r2);
    ushort4 st;
#pragma unroll
    for (int i = 0; i < 4; ++i) {
      float o = w0 * r0[i] + w1 * r0[i + 1] + w2 * r0[i + 2]
              + w3 * r1[i] + w4 * r1[i + 1] + w5 * r1[i + 2]
              + w6 * r2[i] + w7 * r2[i + 1] + w8 * r2[i + 2];
      h16_t ob = f2h(o);
      float of = h2f(ob);
      ssum += of * of;
      if (i == 0) st.x = ob; else if (i == 1) st.y = ob; else if (i == 2) st.z = ob; else st.w = ob;
    }
    *(ushort4*)(op + (y << 7) + x0) = st;
  }
  if (norm2 != nullptr) {
    __shared__ float red[256];
    int tid = threadIdx.x;
    red[tid] = ssum;
    __syncthreads();
    for (int s = 128; s > 0; s >>= 1) {
      if (tid < s) red[tid] += red[tid + s];
      __syncthreads();
    }
    if (tid == 0) norm2[b * DIM + c] = red[0];
  }
}

// ---------------------------------------------------------------------------
// attn Gram: attn[bh][c][d] += sum_n q[b][h*48+c][n] * k[b][h*48+d][n]
// q,k fp16 [b][384][16384] (n-contiguous = K-contiguous: register-direct MFMA)
// grid: (16 K-chunks, 64 bh), block 64 (1 wave, 3x3 16-tiles). fp32 atomics.
// ---------------------------------------------------------------------------
__global__ __launch_bounds__(64) void attn_gemm_kernel(
    const h16_t* __restrict__ q, const h16_t* __restrict__ k, float* __restrict__ attn) {
  int chunk = blockIdx.x, bh = blockIdx.y;
  int b = bh >> 3, h = bh & 7;
  const h16_t* qb = q + ((size_t)(b * DIM + h * CPH) << 14);
  const h16_t* kb = k + ((size_t)(b * DIM + h * CPH) << 14);
  int lane = threadIdx.x;
  int quad = lane >> 4, l15 = lane & 15;
  int off0 = chunk * 1024 + quad * 8;
  floatx4 acc[3][3];
#pragma unroll
  for (int i = 0; i < 3; ++i)
#pragma unroll
    for (int j = 0; j < 3; ++j) acc[i][j] = (floatx4)0.0f;
  for (int s = 0; s < 32; ++s) {
    int off = off0 + s * 32;
    half8 af[3], bfr[3];
#pragma unroll
    for (int i = 0; i < 3; ++i) {
      af[i]  = *(const half8*)(qb + ((size_t)(i * 16 + l15) << 14) + off);
      bfr[i] = *(const half8*)(kb + ((size_t)(i * 16 + l15) << 14) + off);
    }
#pragma unroll
    for (int i = 0; i < 3; ++i)
#pragma unroll
      for (int j = 0; j < 3; ++j)
        acc[i][j] = __builtin_amdgcn_mfma_f32_16x16x32_f16(af[i], bfr[j], acc[i][j], 0, 0, 0);
  }
  float* ap = attn + (size_t)bh * CPH * CPH;
#pragma unroll
  for (int i = 0; i < 3; ++i)
#pragma unroll
    for (int j = 0; j < 3; ++j)
#pragma unroll
      for (int r = 0; r < 4; ++r)
        atomicAdd(&ap[(i * 16 + quad * 4 + r) * CPH + j * 16 + l15], acc[i][j][r]);
}

// ---------------------------------------------------------------------------
// Per-(b,h): scale attn by 1/(|q||k|)*temp, 4x top-m softmax combined with a_mix,
// then fold with proj_w: Bmat[b][o][h*48+d] = sum_c proj_w[o][h*48+c]*Acomb[c][d]
// grid: 64 blocks, 256 threads
// ---------------------------------------------------------------------------
__global__ __launch_bounds__(256) void combine_kernel(
    const float* __restrict__ attn, const float* __restrict__ n2q, const float* __restrict__ n2k,
    const float* __restrict__ temp, const float* __restrict__ amix,
    const float* __restrict__ projw, h16_t* __restrict__ Bmat) {
  int bh = blockIdx.x;
  int b = bh >> 3, h = bh & 7;
  __shared__ float Asc[CPH][CPH];
  __shared__ float Ex[CPH][CPH];
  __shared__ float thr[CPH][4];
  __shared__ float rmax[CPH];
  __shared__ float den[CPH][4];
  __shared__ float rsq[CPH], rsk[CPH];
  int tid = threadIdx.x;
  if (tid < CPH) {
    float nq = sqrtf(n2q[b * DIM + h * CPH + tid]);
    rsq[tid] = 1.f / fmaxf(nq, 1e-12f);
    float nk = sqrtf(n2k[b * DIM + h * CPH + tid]);
    rsk[tid] = 1.f / fmaxf(nk, 1e-12f);
  }
  __syncthreads();
  float tscale = temp[h];
  const float* ap = attn + (size_t)bh * CPH * CPH;
  for (int idx = tid; idx < CPH * CPH; idx += 256) {
    int c = idx / CPH, d = idx - c * CPH;
    Asc[c][d] = ap[idx] * rsq[c] * rsk[d] * tscale;
  }
  __syncthreads();
  const int M0 = 24, M1 = 32, M2 = 36, M3 = 38;  // C//2, 2C//3, 3C//4, 4C//5
  for (int idx = tid; idx < CPH * CPH; idx += 256) {
    int c = idx / CPH, d = idx - c * CPH;
    float a = Asc[c][d];
    int gt = 0, ge = 0;
    float mx = -1e30f;
    for (int e = 0; e < CPH; ++e) {
      float v = Asc[c][e];
      gt += (v > a);
      ge += (v >= a);
      mx = fmaxf(mx, v);
    }
    if (d == 0) rmax[c] = mx;
    // a is the m-th largest iff (#>a) < m <= (#>=a); ties write identical bits
    if (gt < M0 && ge >= M0) thr[c][0] = a;
    if (gt < M1 && ge >= M1) thr[c][1] = a;
    if (gt < M2 && ge >= M2) thr[c][2] = a;
    if (gt < M3 && ge >= M3) thr[c][3] = a;
  }
  __syncthreads();
  for (int idx = tid; idx < CPH * CPH; idx += 256) {
    int c = idx / CPH, d = idx - c * CPH;
    Ex[c][d] = expf(Asc[c][d] - rmax[c]);
  }
  __syncthreads();
  if (tid < CPH * 4) {
    int c = tid >> 2, mi = tid & 3;
    float t_ = thr[c][mi];
    float s = 0.f;
    for (int e = 0; e < CPH; ++e)
      if (Asc[c][e] >= t_) s += Ex[c][e];
    den[c][mi] = s;
  }
  __syncthreads();
  float a0 = amix[0], a1 = amix[1], a2 = amix[2], a3 = amix[3];
  for (int idx = tid; idx < CPH * CPH; idx += 256) {
    int c = idx / CPH, d = idx - c * CPH;
    float a = Asc[c][d];
    float s = 0.f;
    if (a >= thr[c][0]) s += a0 / den[c][0];
    if (a >= thr[c][1]) s += a1 / den[c][1];
    if (a >= thr[c][2]) s += a2 / den[c][2];
    if (a >= thr[c][3]) s += a3 / den[c][3];
    Ex[c][d] = Ex[c][d] * s;  // Acomb
  }
  __syncthreads();
  for (int idx = tid; idx < DIM * CPH; idx += 256) {
    int o = idx / CPH, d = idx - (idx / CPH) * CPH;
    const float* pw = projw + (size_t)o * DIM + h * CPH;
    float s = 0.f;
    for (int c2 = 0; c2 < CPH; ++c2) s += pw[c2] * Ex[c2][d];
    Bmat[((size_t)b * DIM + o) * DIM + h * CPH + d] = f2h(s);
  }
}

// ---------------------------------------------------------------------------
extern "C" void kernel_launch(void* const* d_in, const int* in_sizes, int n_in,
                              void* d_out, int out_size, void* d_ws, size_t ws_size,
                              hipStream_t stream) {
  const float* x_q    = (const float*)d_in[0];
  const float* x_kv   = (const float*)d_in[1];
  const float* q_w    = (const float*)d_in[2];
  const float* q_dw   = (const float*)d_in[3];
  const float* kv_w   = (const float*)d_in[4];
  const float* kv_dw  = (const float*)d_in[5];
  const float* proj_w = (const float*)d_in[6];
  const float* temp   = (const float*)d_in[7];
  const float* amix   = (const float*)d_in[8];

  char* ws = (char*)d_ws;
  const size_t SLOT = (size_t)NBATCH * NPIX * DIM * 2;  // 100,663,296 B
  h16_t* S0 = (h16_t*)(ws);             // Yq -> Yk
  h16_t* S1 = (h16_t*)(ws + SLOT);      // Yv
  h16_t* S2 = (h16_t*)(ws + 2 * SLOT);  // q -> v
  h16_t* S3 = (h16_t*)(ws + 3 * SLOT);  // k
  char* p = ws + 4 * SLOT;
  h16_t* WqB  = (h16_t*)p; p += (size_t)DIM * DIM * 2;
  h16_t* WkvB = (h16_t*)p; p += (size_t)2 * DIM * DIM * 2;
  float* n2q  = (float*)p;  p += (size_t)NBATCH * DIM * 4;
  float* n2k  = (float*)p;  p += (size_t)NBATCH * DIM * 4;
  float* attn = (float*)p;  p += (size_t)64 * CPH * CPH * 4;
  h16_t* Bmat = (h16_t*)p; p += (size_t)NBATCH * DIM * DIM * 2;

  hipMemsetAsync(attn, 0, (size_t)64 * CPH * CPH * 4, stream);

  convert_h16_kernel<<<dim3((DIM * DIM + 255) / 256), 256, 0, stream>>>(q_w, WqB, DIM * DIM);
  convert_h16_kernel<<<dim3((2 * DIM * DIM + 255) / 256), 256, 0, stream>>>(kv_w, WkvB, 2 * DIM * DIM);

  dim3 ggrid(NPIX / 128, DIM / 128, NBATCH);

  // q path (GEMM reads fp32 x_q directly, transposes in LDS)
  gemm_tn_kernel<false, false, float><<<ggrid, 256, 0, stream>>>(WqB, x_q, S0);
  dwconv_kernel<<<dim3(DIM, NBATCH), 256, 0, stream>>>(S0, q_dw, S2, n2q);

  // k and v GEMMs back-to-back: second x_kv read (201 MB < 256 MB L3) hits L3
  gemm_tn_kernel<false, false, float><<<ggrid, 256, 0, stream>>>(WkvB, x_kv, S0);
  gemm_tn_kernel<false, false, float><<<ggrid, 256, 0, stream>>>(WkvB + (size_t)DIM * DIM, x_kv, S1);
  dwconv_kernel<<<dim3(DIM, NBATCH), 256, 0, stream>>>(S0, kv_dw, S3, n2k);

  // attention (48x48 per b,h) + top-m combine + proj fold
  attn_gemm_kernel<<<dim3(16, 64), 64, 0, stream>>>(S2, S3, attn);
  combine_kernel<<<dim3(64), 256, 0, stream>>>(attn, n2q, n2k, temp, amix, proj_w, Bmat);

  // v path (q in S2 is dead after attn)
  dwconv_kernel<<<dim3(DIM, NBATCH), 256, 0, stream>>>(S1, kv_dw + (size_t)DIM * 9, S2, nullptr);

  // fused (proj ∘ attn-mix) @ v -> d_out fp32; B = v fp16 [b][c][n], LDS-transposed
  gemm_tn_kernel<true, true, h16_t><<<ggrid, 256, 0, stream>>>(Bmat, S2, d_out);
}

// Round 3
// 1191.681 us; speedup vs baseline: 1.0334x; 1.0134x over previous
//
#include <hip/hip_runtime.h>
#include <cstdint>
#include <cstddef>
#include <type_traits>

#define DIM 384
#define HEADS 8
#define NBATCH 8
#define NPIX 16384   // 128*128
#define CPH 48       // channels per head

typedef unsigned short h16_t;   // fp16 bits
typedef __attribute__((ext_vector_type(8))) _Float16 half8;
typedef __attribute__((ext_vector_type(4))) float floatx4;

#define VM_WAIT(n) asm volatile("s_waitcnt vmcnt(" #n ")" ::: "memory")
#define LGKM_WAIT0 asm volatile("s_waitcnt lgkmcnt(0)" ::: "memory")

__device__ __forceinline__ h16_t f2h(float f) {
  _Float16 h = (_Float16)f;          // v_cvt_f16_f32, RNE
  return __builtin_bit_cast(h16_t, h);
}
__device__ __forceinline__ float h2f(h16_t u) {
  return (float)__builtin_bit_cast(_Float16, u);
}

__device__ __forceinline__ void gload_lds16(const void* g, void* l) {
  __builtin_amdgcn_global_load_lds(
      (const __attribute__((address_space(1))) unsigned int*)g,
      (__attribute__((address_space(3))) unsigned int*)l, 16, 0, 0);
}

// ---------------------------------------------------------------------------
// fp32 -> fp16 elementwise convert (weights)
// ---------------------------------------------------------------------------
__global__ void convert_h16_kernel(const float* __restrict__ in, h16_t* __restrict__ out, int n) {
  int i = blockIdx.x * blockDim.x + threadIdx.x;
  if (i < n) out[i] = f2h(in[i]);
}

// ---------------------------------------------------------------------------
// B-panel-resident fp16 MFMA GEMM:
//   C[b][m][n] = sum_k A[m][k] * B[b][k][n],  M = MBLKS*128, K = 384
//
// Round-2 post-mortem: in-loop B HBM reads are ~900cyc latency that a depth-1
// prefetch + ~9 waves/CU cannot hide (MfmaUtil 12%, hbm 22%, dur stuck).
// Structural fix: block owns a 64-pixel column slice; the ENTIRE B panel
// [384 k][64 n] is staged to LDS once (fp16, XOR-swizzled chunks, 2-deep
// pipelined fill, full-128B-line loads), then the m/k loop reads only LDS(B)
// and L2(A via global_load_lds double-buffer). Zero HBM waits in the loop.
// B is fetched exactly once per element. SPLIT=true writes rows [0,384) to
// C0 and [384,768) to C1 (fused k+v GEMM sharing one x_kv panel read).
// LDS: lB 48KB + lA 2x16KB = 80KB -> 2 blocks/CU.
// grid: (NPIX/64, NBATCH), block 256 (4 waves; wave tile 64m x 32n per mb)
// ---------------------------------------------------------------------------
template <int MBLKS, bool SPLIT, bool F32OUT, bool ABATCH, typename BT>
__global__ __launch_bounds__(256, 2) void gemm_panel_kernel(
    const h16_t* __restrict__ Aall, const BT* __restrict__ Ball,
    void* __restrict__ C0, void* __restrict__ C1) {
  __shared__ __align__(16) h16_t lB[64 * 384];     // [64 n][48 chunks of 16B], XOR phys
  __shared__ __align__(16) h16_t lA[2][128 * 64];  // [128 m][8 chunks], XOR phys
  constexpr int NP = MBLKS * 6;
  int b = blockIdx.y, nb = blockIdx.x;
  const h16_t* A = Aall + (ABATCH ? (size_t)b * (MBLKS * 128) * DIM : (size_t)0);
  const BT* B = Ball + (size_t)b * DIM * NPIX + (size_t)nb * 64;
  int tid = threadIdx.x;
  int wid = tid >> 6, lane = tid & 63;
  int wm = wid >> 1, wn = wid & 1;
  int quad = lane >> 4, l15 = lane & 15;
  int srow = lane >> 3;                  // 0..7
  int schunk = (lane & 7) ^ srow;        // A XOR swizzle: logical 16B chunk fetched
  int rgrp = tid >> 4;                   // fill: k-octet 0..15
  int n4 = tid & 15;                     // fill: pixel quad 0..15 (n = n4*4..+3)

  using VT = typename std::conditional<sizeof(BT) == 4, float4, ushort4>::type;
  VT va[8], vb[8];

  auto loadStep = [&](int s, VT* arr) {  // step s = 128 k-rows; full-line coalesced
    const BT* bp = B + (size_t)(s * 128 + rgrp * 8) * NPIX + n4 * 4;
#pragma unroll
    for (int i = 0; i < 8; ++i) arr[i] = *(const VT*)(bp + (size_t)i * NPIX);
  };
  auto writeStep = [&](int s, VT* arr) {  // cvt fp16 + transpose into lB
    half8 w0, w1, w2, w3;                 // w_j[i] = half(k = chunk*8+i, n = n4*4+j)
#pragma unroll
    for (int i = 0; i < 8; ++i) {
      if constexpr (sizeof(BT) == 4) {
        w0[i] = (_Float16)arr[i].x; w1[i] = (_Float16)arr[i].y;
        w2[i] = (_Float16)arr[i].z; w3[i] = (_Float16)arr[i].w;
      } else {
        w0[i] = __builtin_bit_cast(_Float16, arr[i].x);
        w1[i] = __builtin_bit_cast(_Float16, arr[i].y);
        w2[i] = __builtin_bit_cast(_Float16, arr[i].z);
        w3[i] = __builtin_bit_cast(_Float16, arr[i].w);
      }
    }
    int chunk = s * 16 + rgrp;            // logical 16B chunk 0..47
#pragma unroll
    for (int j = 0; j < 4; ++j) {
      int n = n4 * 4 + j;
      int phys = chunk ^ (n & 7);
      half8* d = (half8*)((char*)lB + n * 768 + phys * 16);
      *d = (j == 0) ? w0 : (j == 1) ? w1 : (j == 2) ? w2 : w3;
    }
  };
  auto stageA = [&](int p, int buf) {     // A tile [128 m][64 k] for phase p
    int mbn = p / 6, ktn = p - mbn * 6;
    const h16_t* base = A + (size_t)mbn * 128 * DIM + ktn * 64;
#pragma unroll
    for (int t = 0; t < 4; ++t) {
      int r = (wid * 4 + t) * 8 + srow;
      gload_lds16(base + (size_t)r * DIM + schunk * 8,
                  (char*)&lA[buf][0] + (wid * 4 + t) * 1024 + lane * 16);
    }
  };

  // ---- B panel fill (pipelined 2-deep; A tile 0 issued first) ----
  stageA(0, 0);
  loadStep(0, va);
  loadStep(1, vb);
  VM_WAIT(8);                 // va ready (A0 + va drained; vb in flight)
  __builtin_amdgcn_sched_barrier(0);
  writeStep(0, va);
  loadStep(2, va);
  VM_WAIT(8);                 // vb ready (va' in flight)
  __builtin_amdgcn_sched_barrier(0);
  writeStep(1, vb);
  VM_WAIT(0);                 // va' ready; A0 long done
  __builtin_amdgcn_sched_barrier(0);
  writeStep(2, va);
  LGKM_WAIT0;                 // my ds_writes visible
  __builtin_amdgcn_sched_barrier(0);
  __builtin_amdgcn_s_barrier();  // panel + A0 complete for all waves

  // ---- m/k phase loop: LDS-only B, L2 dbuf A ----
  floatx4 acc[4][2];
  int pb = 0;
  for (int p = 0; p < NP; ++p) {
    int mb = p / 6, kt = p - mb * 6;
    if (p + 1 < NP) {
      stageA(p + 1, pb ^ 1);
      VM_WAIT(4);             // A(p) deposits done; A(p+1) (+stores) drain behind
    } else {
      VM_WAIT(0);
    }
    __builtin_amdgcn_sched_barrier(0);
    __builtin_amdgcn_s_barrier();  // all waves' A(p) deposits visible
    if (kt == 0) {
#pragma unroll
      for (int i = 0; i < 4; ++i)
#pragma unroll
        for (int j = 0; j < 2; ++j) acc[i][j] = (floatx4)0.0f;
    }
    const char* la = (const char*)&lA[pb][0];
#pragma unroll
    for (int ks = 0; ks < 2; ++ks) {
      half8 af[4], bfr[2];
      int ph = (((ks << 2) | quad) ^ (l15 & 7)) << 4;  // A phys chunk byte
#pragma unroll
      for (int i = 0; i < 4; ++i)
        af[i] = *(const half8*)(la + (wm * 64 + i * 16 + l15) * 128 + ph);
#pragma unroll
      for (int j = 0; j < 2; ++j) {
        int n = wn * 32 + j * 16 + l15;
        int phys = (kt * 8 + ks * 4 + quad) ^ (l15 & 7);
        bfr[j] = *(const half8*)((const char*)lB + n * 768 + phys * 16);
      }
#pragma unroll
      for (int i = 0; i < 4; ++i)
#pragma unroll
        for (int j = 0; j < 2; ++j)
          acc[i][j] = __builtin_amdgcn_mfma_f32_16x16x32_f16(af[i], bfr[j], acc[i][j], 0, 0, 0);
    }
    if (kt == 5) {  // epilogue for this mb (stores drain behind next VM_WAIT)
      int orow0 = mb * 128 + wm * 64 + quad * 4;
      int ncol0 = nb * 64 + wn * 32 + l15;
      char* dst;
      int m0;
      if (SPLIT && mb >= 3) { dst = (char*)C1; m0 = orow0 - 384; }
      else                  { dst = (char*)C0; m0 = orow0; }
#pragma unroll
      for (int i = 0; i < 4; ++i) {
#pragma unroll
        for (int j = 0; j < 2; ++j) {
#pragma unroll
          for (int r = 0; r < 4; ++r) {
            size_t idx = ((size_t)b * DIM + (m0 + i * 16 + r)) * NPIX + (ncol0 + j * 16);
            if (F32OUT)
              ((float*)dst)[idx] = acc[i][j][r];
            else
              ((h16_t*)dst)[idx] = f2h(acc[i][j][r]);
          }
        }
      }
    }
    LGKM_WAIT0;               // my lds reads done before next phase overwrites lA
    __builtin_amdgcn_sched_barrier(0);
    __builtin_amdgcn_s_barrier();
    pb ^= 1;
  }
}

// ---------------------------------------------------------------------------
// Depthwise 3x3, SAME padding, fp16 in/out, fp32 weights & arithmetic.
// Optionally accumulates sum of squares (of the fp16-rounded outputs) per plane.
// grid: (C=384, b=8), block 256. Each block = one (b,c) 128x128 plane.
// ---------------------------------------------------------------------------
__device__ __forceinline__ void load_row6(const h16_t* ip, int yy, int x0, float* r) {
  if ((unsigned)yy > 127u) {
    r[0] = r[1] = r[2] = r[3] = r[4] = r[5] = 0.f;
    return;
  }
  const h16_t* row = ip + (yy << 7) + x0;
  ushort4 m = *(const ushort4*)row;
  r[0] = (x0 > 0) ? h2f(row[-1]) : 0.f;
  r[1] = h2f(m.x); r[2] = h2f(m.y); r[3] = h2f(m.z); r[4] = h2f(m.w);
  r[5] = (x0 < 124) ? h2f(row[4]) : 0.f;
}

__global__ __launch_bounds__(256) void dwconv_kernel(
    const h16_t* __restrict__ in, const float* __restrict__ wbase,
    h16_t* __restrict__ out, float* __restrict__ norm2) {
  int c = blockIdx.x, b = blockIdx.y;
  const h16_t* ip = in + ((size_t)(b * DIM + c) << 14);
  h16_t* op = out + ((size_t)(b * DIM + c) << 14);
  const float* wp = wbase + c * 9;
  float w0 = wp[0], w1 = wp[1], w2 = wp[2], w3 = wp[3], w4 = wp[4];
  float w5 = wp[5], w6 = wp[6], w7 = wp[7], w8 = wp[8];
  float ssum = 0.f;
  for (int t = threadIdx.x; t < 4096; t += 256) {
    int y = t >> 5;
    int x0 = (t & 31) << 2;
    float r0[6], r1[6], r2[6];
    load_row6(ip, y - 1, x0, r0);
    load_row6(ip, y,     x0, r1);
    load_row6(ip, y + 1, x0, r2);
    ushort4 st;
#pragma unroll
    for (int i = 0; i < 4; ++i) {
      float o = w0 * r0[i] + w1 * r0[i + 1] + w2 * r0[i + 2]
              + w3 * r1[i] + w4 * r1[i + 1] + w5 * r1[i + 2]
              + w6 * r2[i] + w7 * r2[i + 1] + w8 * r2[i + 2];
      h16_t ob = f2h(o);
      float of = h2f(ob);
      ssum += of * of;
      if (i == 0) st.x = ob; else if (i == 1) st.y = ob; else if (i == 2) st.z = ob; else st.w = ob;
    }
    *(ushort4*)(op + (y << 7) + x0) = st;
  }
  if (norm2 != nullptr) {
    __shared__ float red[256];
    int tid = threadIdx.x;
    red[tid] = ssum;
    __syncthreads();
    for (int s = 128; s > 0; s >>= 1) {
      if (tid < s) red[tid] += red[tid + s];
      __syncthreads();
    }
    if (tid == 0) norm2[b * DIM + c] = red[0];
  }
}

// ---------------------------------------------------------------------------
// attn Gram: attn[bh][c][d] += sum_n q[b][h*48+c][n] * k[b][h*48+d][n]
// q,k fp16 [b][384][16384] (n-contiguous = K-contiguous: register-direct MFMA)
// grid: (16 K-chunks, 64 bh), block 64 (1 wave, 3x3 16-tiles). fp32 atomics.
// ---------------------------------------------------------------------------
__global__ __launch_bounds__(64) void attn_gemm_kernel(
    const h16_t* __restrict__ q, const h16_t* __restrict__ k, float* __restrict__ attn) {
  int chunk = blockIdx.x, bh = blockIdx.y;
  int b = bh >> 3, h = bh & 7;
  const h16_t* qb = q + ((size_t)(b * DIM + h * CPH) << 14);
  const h16_t* kb = k + ((size_t)(b * DIM + h * CPH) << 14);
  int lane = threadIdx.x;
  int quad = lane >> 4, l15 = lane & 15;
  int off0 = chunk * 1024 + quad * 8;
  floatx4 acc[3][3];
#pragma unroll
  for (int i = 0; i < 3; ++i)
#pragma unroll
    for (int j = 0; j < 3; ++j) acc[i][j] = (floatx4)0.0f;
  for (int s = 0; s < 32; ++s) {
    int off = off0 + s * 32;
    half8 af[3], bfr[3];
#pragma unroll
    for (int i = 0; i < 3; ++i) {
      af[i]  = *(const half8*)(qb + ((size_t)(i * 16 + l15) << 14) + off);
      bfr[i] = *(const half8*)(kb + ((size_t)(i * 16 + l15) << 14) + off);
    }
#pragma unroll
    for (int i = 0; i < 3; ++i)
#pragma unroll
      for (int j = 0; j < 3; ++j)
        acc[i][j] = __builtin_amdgcn_mfma_f32_16x16x32_f16(af[i], bfr[j], acc[i][j], 0, 0, 0);
  }
  float* ap = attn + (size_t)bh * CPH * CPH;
#pragma unroll
  for (int i = 0; i < 3; ++i)
#pragma unroll
    for (int j = 0; j < 3; ++j)
#pragma unroll
      for (int r = 0; r < 4; ++r)
        atomicAdd(&ap[(i * 16 + quad * 4 + r) * CPH + j * 16 + l15], acc[i][j][r]);
}

// ---------------------------------------------------------------------------
// Per-(b,h): scale attn by 1/(|q||k|)*temp, 4x top-m softmax combined with a_mix,
// then fold with proj_w: Bmat[b][o][h*48+d] = sum_c proj_w[o][h*48+c]*Acomb[c][d]
// grid: 64 blocks, 256 threads
// ---------------------------------------------------------------------------
__global__ __launch_bounds__(256) void combine_kernel(
    const float* __restrict__ attn, const float* __restrict__ n2q, const float* __restrict__ n2k,
    const float* __restrict__ temp, const float* __restrict__ amix,
    const float* __restrict__ projw, h16_t* __restrict__ Bmat) {
  int bh = blockIdx.x;
  int b = bh >> 3, h = bh & 7;
  __shared__ float Asc[CPH][CPH];
  __shared__ float Ex[CPH][CPH];
  __shared__ float thr[CPH][4];
  __shared__ float rmax[CPH];
  __shared__ float den[CPH][4];
  __shared__ float rsq[CPH], rsk[CPH];
  int tid = threadIdx.x;
  if (tid < CPH) {
    float nq = sqrtf(n2q[b * DIM + h * CPH + tid]);
    rsq[tid] = 1.f / fmaxf(nq, 1e-12f);
    float nk = sqrtf(n2k[b * DIM + h * CPH + tid]);
    rsk[tid] = 1.f / fmaxf(nk, 1e-12f);
  }
  __syncthreads();
  float tscale = temp[h];
  const float* ap = attn + (size_t)bh * CPH * CPH;
  for (int idx = tid; idx < CPH * CPH; idx += 256) {
    int c = idx / CPH, d = idx - c * CPH;
    Asc[c][d] = ap[idx] * rsq[c] * rsk[d] * tscale;
  }
  __syncthreads();
  const int M0 = 24, M1 = 32, M2 = 36, M3 = 38;  // C//2, 2C//3, 3C//4, 4C//5
  for (int idx = tid; idx < CPH * CPH; idx += 256) {
    int c = idx / CPH, d = idx - c * CPH;
    float a = Asc[c][d];
    int gt = 0, ge = 0;
    float mx = -1e30f;
    for (int e = 0; e < CPH; ++e) {
      float v = Asc[c][e];
      gt += (v > a);
      ge += (v >= a);
      mx = fmaxf(mx, v);
    }
    if (d == 0) rmax[c] = mx;
    // a is the m-th largest iff (#>a) < m <= (#>=a); ties write identical bits
    if (gt < M0 && ge >= M0) thr[c][0] = a;
    if (gt < M1 && ge >= M1) thr[c][1] = a;
    if (gt < M2 && ge >= M2) thr[c][2] = a;
    if (gt < M3 && ge >= M3) thr[c][3] = a;
  }
  __syncthreads();
  for (int idx = tid; idx < CPH * CPH; idx += 256) {
    int c = idx / CPH, d = idx - c * CPH;
    Ex[c][d] = expf(Asc[c][d] - rmax[c]);
  }
  __syncthreads();
  if (tid < CPH * 4) {
    int c = tid >> 2, mi = tid & 3;
    float t_ = thr[c][mi];
    float s = 0.f;
    for (int e = 0; e < CPH; ++e)
      if (Asc[c][e] >= t_) s += Ex[c][e];
    den[c][mi] = s;
  }
  __syncthreads();
  float a0 = amix[0], a1 = amix[1], a2 = amix[2], a3 = amix[3];
  for (int idx = tid; idx < CPH * CPH; idx += 256) {
    int c = idx / CPH, d = idx - c * CPH;
    float a = Asc[c][d];
    float s = 0.f;
    if (a >= thr[c][0]) s += a0 / den[c][0];
    if (a >= thr[c][1]) s += a1 / den[c][1];
    if (a >= thr[c][2]) s += a2 / den[c][2];
    if (a >= thr[c][3]) s += a3 / den[c][3];
    Ex[c][d] = Ex[c][d] * s;  // Acomb
  }
  __syncthreads();
  for (int idx = tid; idx < DIM * CPH; idx += 256) {
    int o = idx / CPH, d = idx - (idx / CPH) * CPH;
    const float* pw = projw + (size_t)o * DIM + h * CPH;
    float s = 0.f;
    for (int c2 = 0; c2 < CPH; ++c2) s += pw[c2] * Ex[c2][d];
    Bmat[((size_t)b * DIM + o) * DIM + h * CPH + d] = f2h(s);
  }
}

// ---------------------------------------------------------------------------
extern "C" void kernel_launch(void* const* d_in, const int* in_sizes, int n_in,
                              void* d_out, int out_size, void* d_ws, size_t ws_size,
                              hipStream_t stream) {
  const float* x_q    = (const float*)d_in[0];
  const float* x_kv   = (const float*)d_in[1];
  const float* q_w    = (const float*)d_in[2];
  const float* q_dw   = (const float*)d_in[3];
  const float* kv_w   = (const float*)d_in[4];
  const float* kv_dw  = (const float*)d_in[5];
  const float* proj_w = (const float*)d_in[6];
  const float* temp   = (const float*)d_in[7];
  const float* amix   = (const float*)d_in[8];

  char* ws = (char*)d_ws;
  const size_t SLOT = (size_t)NBATCH * NPIX * DIM * 2;  // 100,663,296 B
  h16_t* S0 = (h16_t*)(ws);             // Yq -> Yk
  h16_t* S1 = (h16_t*)(ws + SLOT);      // Yv
  h16_t* S2 = (h16_t*)(ws + 2 * SLOT);  // q -> v
  h16_t* S3 = (h16_t*)(ws + 3 * SLOT);  // k
  char* p = ws + 4 * SLOT;
  h16_t* WqB  = (h16_t*)p; p += (size_t)DIM * DIM * 2;
  h16_t* WkvB = (h16_t*)p; p += (size_t)2 * DIM * DIM * 2;
  float* n2q  = (float*)p;  p += (size_t)NBATCH * DIM * 4;
  float* n2k  = (float*)p;  p += (size_t)NBATCH * DIM * 4;
  float* attn = (float*)p;  p += (size_t)64 * CPH * CPH * 4;
  h16_t* Bmat = (h16_t*)p; p += (size_t)NBATCH * DIM * DIM * 2;

  hipMemsetAsync(attn, 0, (size_t)64 * CPH * CPH * 4, stream);

  convert_h16_kernel<<<dim3((DIM * DIM + 255) / 256), 256, 0, stream>>>(q_w, WqB, DIM * DIM);
  convert_h16_kernel<<<dim3((2 * DIM * DIM + 255) / 256), 256, 0, stream>>>(kv_w, WkvB, 2 * DIM * DIM);

  dim3 pgrid(NPIX / 64, NBATCH);

  // q path: B panel = x_q (fp32), A = Wq
  gemm_panel_kernel<3, false, false, false, float><<<pgrid, 256, 0, stream>>>(WqB, x_q, S0, nullptr);
  dwconv_kernel<<<dim3(DIM, NBATCH), 256, 0, stream>>>(S0, q_dw, S2, n2q);

  // fused k+v: one x_kv panel read, M=768 (Wk rows 0..383 -> S0, Wv rows 384..767 -> S1)
  gemm_panel_kernel<6, true, false, false, float><<<pgrid, 256, 0, stream>>>(WkvB, x_kv, S0, S1);
  dwconv_kernel<<<dim3(DIM, NBATCH), 256, 0, stream>>>(S0, kv_dw, S3, n2k);

  // attention (48x48 per b,h) + top-m combine + proj fold
  attn_gemm_kernel<<<dim3(16, 64), 64, 0, stream>>>(S2, S3, attn);
  combine_kernel<<<dim3(64), 256, 0, stream>>>(attn, n2q, n2k, temp, amix, proj_w, Bmat);

  // v path (q in S2 dead after attn)
  dwconv_kernel<<<dim3(DIM, NBATCH), 256, 0, stream>>>(S1, kv_dw + (size_t)DIM * 9, S2, nullptr);

  // fused (proj o attn-mix) @ v -> d_out fp32; B panel = v fp16
  gemm_panel_kernel<3, false, true, true, h16_t><<<pgrid, 256, 0, stream>>>(Bmat, S2, d_out, nullptr);
}